// Round 3
// baseline (83.992 us; speedup 1.0000x reference)
//
#include <hip/hip_runtime.h>
#include <math.h>

#define NROW 768
#define DIM  128

constexpr int H0c  = 256;
constexpr int H1c  = 362;
constexpr int HP1c = 368;   // H1 padded; pad columns are exact zeros

// Workspace layout (float offsets). ~3.9 MB total.
// hx stored in PANEL layout: [HP/4][768][4] so the pair kernel's per-thread
// read hx[i, hb..hb+3] is one coalesced float4 (lane = i).
constexpr int HX0_OFF  = 0;         // [64][768][4]
constexpr int HYB0_OFF = 196608;    // [768][256]   hy0 + b1_0 (row-major)
constexpr int HX1_OFF  = 393216;    // [92][768][4]
constexpr int HYB1_OFF = 675840;    // [768][368]   hy1 + b1_1 (row-major)
constexpr int PMAX_OFF = 958464;    // [2][768][4]  (slots 0..2 used)
constexpr int PSUM_OFF = 964608;    // [2][768][4]
constexpr int DIAG_OFF = 970752;    // [2][768]  s_diag = 0.5*(u_i + A_ii)
constexpr int UH_OFF   = 972288;    // [2][768]  0.5*u_i

// ---------------------------------------------------------------------------
// prep: four projections, templated so K is constexpr (unrolled, pipelined).
//   M=0: hx0  = s0 @ W1_0[0:128]            -> panel
//   M=1: hyb0 = s1 @ W1_0[128:256] + b1_0   -> row-major
//   M=2: hx1  = [s0|s1] @ W1_1[0:256]       -> panel
//   M=3: hyb1 = s2 @ W1_1[256:384] + b1_1   -> row-major
// block = (64 h, 8 row-groups) = 512 thr; thread: 4 h x 2 rows.
// ---------------------------------------------------------------------------
template <int M, int HT>
__device__ __forceinline__ void prep_body(
    const float* __restrict__ s0, const float* __restrict__ s1, const float* __restrict__ s2,
    const float* __restrict__ W1_0, const float* __restrict__ b1_0,
    const float* __restrict__ W1_1, const float* __restrict__ b1_1,
    float* __restrict__ ws, float* __restrict__ xs) {
  constexpr int K     = (M == 2) ? 256 : 128;
  constexpr int HREAL = (M <= 1) ? H0c : H1c;
  constexpr int WOFF  = (M == 1) ? 128 : (M == 3) ? 256 : 0;
  constexpr int HACT  = (M <= 1) ? 256 : 184;   // h-range per HT tile

  const float* __restrict__ W    = (M <= 1) ? W1_0 : W1_1;
  const float* __restrict__ bias = (M == 1) ? b1_0 : (M == 3) ? b1_1 : nullptr;

  const int i0  = blockIdx.x * 16;
  const int tx  = threadIdx.x;            // 0..63
  const int ty  = threadIdx.y;            // 0..7
  const int tid = ty * 64 + tx;

  // stage 16 input rows into LDS (M==2 concatenates s0|s1)
  {
    const float* __restrict__ sa = (M == 3) ? s2 : (M == 1) ? s1 : s0;
    constexpr int NF4 = 16 * (K / 4);
    for (int idx = tid; idx < NF4; idx += 512) {
      const int row = idx / (K / 4);
      const int c4  = (idx % (K / 4)) * 4;
      float4 v;
      if (M == 2 && c4 >= DIM)
        v = *(const float4*)&s1[(i0 + row) * DIM + (c4 - DIM)];
      else
        v = *(const float4*)&sa[(i0 + row) * DIM + c4];
      *(float4*)&xs[row * K + c4] = v;
    }
  }
  __syncthreads();

  if (tx * 4 >= HACT) return;
  const int h4 = HT * HACT + tx * 4;
  const bool fullw = (h4 + 4 <= HREAL);   // tail lane for H1 (h4==360)

  const int r0 = ty * 2;
  float acc[2][4] = {};
  const float* __restrict__ Wb = W + WOFF * HREAL + h4;

  #pragma unroll 2
  for (int d = 0; d < K; d += 4) {
    const float4 xv0 = *(const float4*)&xs[(r0 + 0) * K + d];
    const float4 xv1 = *(const float4*)&xs[(r0 + 1) * K + d];
    float4 wv[4];
    #pragma unroll
    for (int dd = 0; dd < 4; ++dd) {
      if (fullw) {
        wv[dd] = *(const float4*)&Wb[(d + dd) * HREAL];
      } else {
        wv[dd].x = (h4 + 0 < HREAL) ? Wb[(d + dd) * HREAL + 0] : 0.f;
        wv[dd].y = (h4 + 1 < HREAL) ? Wb[(d + dd) * HREAL + 1] : 0.f;
        wv[dd].z = 0.f; wv[dd].w = 0.f;
      }
    }
    #pragma unroll
    for (int dd = 0; dd < 4; ++dd) {
      const float x0 = ((const float*)&xv0)[dd];
      const float x1 = ((const float*)&xv1)[dd];
      acc[0][0] = fmaf(x0, wv[dd].x, acc[0][0]);
      acc[0][1] = fmaf(x0, wv[dd].y, acc[0][1]);
      acc[0][2] = fmaf(x0, wv[dd].z, acc[0][2]);
      acc[0][3] = fmaf(x0, wv[dd].w, acc[0][3]);
      acc[1][0] = fmaf(x1, wv[dd].x, acc[1][0]);
      acc[1][1] = fmaf(x1, wv[dd].y, acc[1][1]);
      acc[1][2] = fmaf(x1, wv[dd].z, acc[1][2]);
      acc[1][3] = fmaf(x1, wv[dd].w, acc[1][3]);
    }
  }

  const bool ok0 = (h4 + 0 < HREAL), ok1 = (h4 + 1 < HREAL),
             ok2 = (h4 + 2 < HREAL), ok3 = (h4 + 3 < HREAL);
  float bv[4] = {0.f, 0.f, 0.f, 0.f};
  if (M == 1 || M == 3) {
    if (ok0) bv[0] = bias[h4 + 0];
    if (ok1) bv[1] = bias[h4 + 1];
    if (ok2) bv[2] = bias[h4 + 2];
    if (ok3) bv[3] = bias[h4 + 3];
  }

  float* __restrict__ outp = ws + ((M == 0) ? HX0_OFF : (M == 1) ? HYB0_OFF
                                 : (M == 2) ? HX1_OFF : HYB1_OFF);
  if ((M & 1) == 0) {   // panel layout
    const int pbase = (h4 >> 2) * (NROW * 4);
    #pragma unroll
    for (int r = 0; r < 2; ++r) {
      float4 v;
      v.x = ok0 ? acc[r][0] : 0.f;
      v.y = ok1 ? acc[r][1] : 0.f;
      v.z = ok2 ? acc[r][2] : 0.f;
      v.w = ok3 ? acc[r][3] : 0.f;
      *(float4*)&outp[pbase + (i0 + r0 + r) * 4] = v;
    }
  } else {              // row-major + bias
    constexpr int HP = (M <= 1) ? H0c : HP1c;
    #pragma unroll
    for (int r = 0; r < 2; ++r) {
      float4 v;
      v.x = ok0 ? acc[r][0] + bv[0] : 0.f;
      v.y = ok1 ? acc[r][1] + bv[1] : 0.f;
      v.z = ok2 ? acc[r][2] + bv[2] : 0.f;
      v.w = ok3 ? acc[r][3] + bv[3] : 0.f;
      *(float4*)&outp[(i0 + r0 + r) * HP + h4] = v;
    }
  }
}

__global__ __launch_bounds__(512) void prep_kernel(
    const float* __restrict__ s0, const float* __restrict__ s1, const float* __restrict__ s2,
    const float* __restrict__ W1_0, const float* __restrict__ b1_0,
    const float* __restrict__ W1_1, const float* __restrict__ b1_1,
    float* __restrict__ ws) {
  __shared__ float xs[16 * 256];
  switch (blockIdx.y) {
    case 0: prep_body<0, 0>(s0, s1, s2, W1_0, b1_0, W1_1, b1_1, ws, xs); break;
    case 1: prep_body<1, 0>(s0, s1, s2, W1_0, b1_0, W1_1, b1_1, ws, xs); break;
    case 2: prep_body<2, 0>(s0, s1, s2, W1_0, b1_0, W1_1, b1_1, ws, xs); break;
    case 3: prep_body<2, 1>(s0, s1, s2, W1_0, b1_0, W1_1, b1_1, ws, xs); break;
    case 4: prep_body<3, 0>(s0, s1, s2, W1_0, b1_0, W1_1, b1_1, ws, xs); break;
    default: prep_body<3, 1>(s0, s1, s2, W1_0, b1_0, W1_1, b1_1, ws, xs); break;
  }
}

// ---------------------------------------------------------------------------
// uv: uh[est][i] = 0.5 * sum_h W2[h] * hx[i,h].  One wave per row.
// (v_j = sum_h W2[h]*hyb[j,h] cancels exactly between t0 and lse; not needed.)
// ---------------------------------------------------------------------------
__global__ __launch_bounds__(256) void uv_kernel(
    const float* __restrict__ W2_0, const float* __restrict__ W2_1,
    float* __restrict__ ws) {
  const int lane = threadIdx.x & 63;
  const int gw   = blockIdx.x * 4 + (threadIdx.x >> 6);  // 0..1535
  const int est  = gw >= NROW;
  const int i    = gw - est * NROW;

  const float* __restrict__ hx4 = ws + (est ? HX1_OFF : HX0_OFF);
  const float* __restrict__ W2  = est ? W2_1 : W2_0;
  const int HP    = est ? HP1c : H0c;
  const int HREAL = est ? H1c : H0c;

  float sum = 0.f;
  for (int h = lane; h < HP; h += 64) {
    if (h < HREAL) {
      const float x = hx4[(h >> 2) * (NROW * 4) + i * 4 + (h & 3)];
      sum = fmaf(x, W2[h], sum);
    }
  }
  #pragma unroll
  for (int off = 32; off > 0; off >>= 1) sum += __shfl_xor(sum, off);
  if (lane == 0) ws[UH_OFF + est * NROW + i] = 0.5f * sum;
}

// ---------------------------------------------------------------------------
// pair: A[j,i] = sum_h w_h * |hx[i,h] + hyb[j,h]|; s = 0.5*A + uh_i;
// per-row partial max / sum-exp over i.  2 VALU instrs per element
// (v_add_f32 + v_fma_f32 with |.| source modifier).
// Block = 6 j-rows x 256 i; grid 128 x 3 x 2 = 768 blocks (3/CU exact).
// ---------------------------------------------------------------------------
template <int HP, int HREAL>
__device__ __forceinline__ void pair_body(
    const float* __restrict__ hx4, const float* __restrict__ hyb,
    const float* __restrict__ W2, const float* __restrict__ uh,
    float* __restrict__ pmax, float* __restrict__ psum, float* __restrict__ sdiag,
    float* sh) {
  float* ys   = sh;             // [6][HP]
  float* w2s  = sh + 6 * HP;    // [HP]
  float* redm = w2s + HP;       // [4][6]
  float* reds = redm + 24;      // [4][6]

  const int tid = threadIdx.x;          // 0..255
  const int j0  = blockIdx.x * 6;
  const int iq  = blockIdx.y;           // 0..2
  const int i   = iq * 256 + tid;

  for (int idx = tid; idx < 6 * (HP / 4); idx += 256) {
    const int row = idx / (HP / 4);
    const int c4  = (idx % (HP / 4)) * 4;
    *(float4*)&ys[row * HP + c4] = *(const float4*)&hyb[(j0 + row) * HP + c4];
  }
  for (int h = tid; h < HP; h += 256)
    w2s[h] = (h < HREAL) ? W2[h] : 0.f;
  __syncthreads();

  const float uh_i = uh[i];

  float acc[6] = {0.f, 0.f, 0.f, 0.f, 0.f, 0.f};
  const float* xp = hx4 + i * 4;
  #pragma unroll 2
  for (int hb = 0; hb < HP; hb += 4, xp += NROW * 4) {
    const float4 a = *(const float4*)xp;
    const float4 w = *(const float4*)&w2s[hb];
    #pragma unroll
    for (int r = 0; r < 6; ++r) {
      const float4 y = *(const float4*)&ys[r * HP + hb];
      acc[r] = fmaf(fabsf(a.x + y.x), w.x, acc[r]);
      acc[r] = fmaf(fabsf(a.y + y.y), w.y, acc[r]);
      acc[r] = fmaf(fabsf(a.z + y.z), w.z, acc[r]);
      acc[r] = fmaf(fabsf(a.w + y.w), w.w, acc[r]);
    }
  }

  float s[6];
  #pragma unroll
  for (int r = 0; r < 6; ++r) s[r] = fmaf(0.5f, acc[r], uh_i);

  // diagonal s (t0 path; v_j cancels against lse, b2 cancels too)
  const int dj = i - j0;
  #pragma unroll
  for (int r = 0; r < 6; ++r)
    if (dj == r) sdiag[i] = s[r];

  const int lane = tid & 63;
  const int wv   = tid >> 6;

  float M[6];
  #pragma unroll
  for (int r = 0; r < 6; ++r) {
    float mm = s[r];
    #pragma unroll
    for (int off = 32; off > 0; off >>= 1) mm = fmaxf(mm, __shfl_xor(mm, off));
    M[r] = mm;
  }
  if (lane == 0) {
    #pragma unroll
    for (int r = 0; r < 6; ++r) redm[wv * 6 + r] = M[r];
  }
  __syncthreads();
  #pragma unroll
  for (int r = 0; r < 6; ++r)
    M[r] = fmaxf(fmaxf(redm[r], redm[6 + r]), fmaxf(redm[12 + r], redm[18 + r]));

  #pragma unroll
  for (int r = 0; r < 6; ++r) {
    float e = __expf(s[r] - M[r]);
    #pragma unroll
    for (int off = 32; off > 0; off >>= 1) e += __shfl_xor(e, off);
    if (lane == 0) reds[wv * 6 + r] = e;
  }
  __syncthreads();
  if (tid < 6) {
    const float m = fmaxf(fmaxf(redm[tid], redm[6 + tid]),
                          fmaxf(redm[12 + tid], redm[18 + tid]));
    const float sm = reds[tid] + reds[6 + tid] + reds[12 + tid] + reds[18 + tid];
    pmax[(j0 + tid) * 4 + iq] = m;
    psum[(j0 + tid) * 4 + iq] = sm;
  }
}

__global__ __launch_bounds__(256) void pair_kernel(
    float* __restrict__ ws, const float* __restrict__ W2_0, const float* __restrict__ W2_1) {
  __shared__ float sh[6 * HP1c + HP1c + 48];
  if (blockIdx.z == 0)
    pair_body<H0c, H0c>(ws + HX0_OFF, ws + HYB0_OFF, W2_0, ws + UH_OFF,
                        ws + PMAX_OFF, ws + PSUM_OFF, ws + DIAG_OFF, sh);
  else
    pair_body<HP1c, H1c>(ws + HX1_OFF, ws + HYB1_OFF, W2_1, ws + UH_OFF + NROW,
                         ws + PMAX_OFF + 3072, ws + PSUM_OFF + 3072, ws + DIAG_OFF + NROW, sh);
}

// ---------------------------------------------------------------------------
// final: merge 3 i-quarter partials -> lse_s per row; sum (s_diag - lse_s).
// ---------------------------------------------------------------------------
__global__ __launch_bounds__(1024) void final_kernel(
    const float* __restrict__ ws, float* __restrict__ out) {
  __shared__ float red[1024];
  const int t = threadIdx.x;
  float val = 0.f;
  if (t < NROW) {
    #pragma unroll
    for (int est = 0; est < 2; ++est) {
      const float* pm = ws + PMAX_OFF + est * 3072 + t * 4;
      const float* ps = ws + PSUM_OFF + est * 3072 + t * 4;
      float M = fmaxf(fmaxf(pm[0], pm[1]), pm[2]);
      float S = ps[0] * __expf(pm[0] - M) + ps[1] * __expf(pm[1] - M) +
                ps[2] * __expf(pm[2] - M);
      float lse = M + logf(S);
      val += ws[DIAG_OFF + est * NROW + t] - lse;
    }
  }
  red[t] = val;
  __syncthreads();
  for (int sdown = 512; sdown > 0; sdown >>= 1) {
    if (t < sdown) red[t] += red[t + sdown];
    __syncthreads();
  }
  if (t == 0) out[0] = red[0] * (1.0f / (float)NROW) + 2.0f * logf((float)NROW);
}

// ---------------------------------------------------------------------------
extern "C" void kernel_launch(void* const* d_in, const int* in_sizes, int n_in,
                              void* d_out, int out_size, void* d_ws, size_t ws_size,
                              hipStream_t stream) {
  const float* s0   = (const float*)d_in[0];
  const float* s1   = (const float*)d_in[1];
  const float* s2   = (const float*)d_in[2];
  const float* W1_0 = (const float*)d_in[3];
  const float* b1_0 = (const float*)d_in[4];
  const float* W2_0 = (const float*)d_in[5];
  const float* W1_1 = (const float*)d_in[7];
  const float* b1_1 = (const float*)d_in[8];
  const float* W2_1 = (const float*)d_in[9];
  float* ws  = (float*)d_ws;
  float* out = (float*)d_out;

  hipLaunchKernelGGL(prep_kernel, dim3(48, 6), dim3(64, 8), 0, stream,
                     s0, s1, s2, W1_0, b1_0, W1_1, b1_1, ws);
  hipLaunchKernelGGL(uv_kernel, dim3(384), dim3(256), 0, stream, W2_0, W2_1, ws);
  hipLaunchKernelGGL(pair_kernel, dim3(128, 3, 2), dim3(256), 0, stream,
                     ws, W2_0, W2_1);
  hipLaunchKernelGGL(final_kernel, dim3(1), dim3(1024), 0, stream, ws, out);
}

// Round 5
// 83.210 us; speedup vs baseline: 1.0094x; 1.0094x over previous
//
#include <hip/hip_runtime.h>
#include <math.h>

#define NROW 768
#define DIM  128

constexpr int H0c  = 256;
constexpr int H1c  = 362;
constexpr int HP1c = 368;   // H1 padded; pad columns are exact zeros

// Workspace layout (float offsets). ~3.9 MB total.
// hx stored in PANEL layout: [HP/4][768][4] so the pair kernel's per-thread
// read hx[i, hb..hb+3] is one coalesced float4 (lane = i).
constexpr int HX0_OFF  = 0;         // [64][768][4]
constexpr int HYB0_OFF = 196608;    // [768][256]   hy0 + b1_0 (row-major)
constexpr int HX1_OFF  = 393216;    // [92][768][4]
constexpr int HYB1_OFF = 675840;    // [768][368]   hy1 + b1_1 (row-major)
constexpr int PMAX_OFF = 958464;    // [2][768][2]  per-iq-half row max
constexpr int PSUM_OFF = 961536;    // [2][768][2]
constexpr int DIAG_OFF = 964608;    // [2][768]     s_diag
constexpr int UHP_OFF  = 966144;    // [2][2][768]  u partials (est, ht)

// ---------------------------------------------------------------------------
// prep: four projections (256 thr, 4h x 4rows, 16 fma chains / thread).
//   M=0: hx0  = s0 @ W1_0[0:128]            -> panel  (+ u0 partial)
//   M=1: hyb0 = s1 @ W1_0[128:256] + b1_0   -> row-major
//   M=2: hx1  = [s0|s1] @ W1_1[0:256]       -> panel  (+ u1 partials)
//   M=3: hyb1 = s2 @ W1_1[256:384] + b1_1   -> row-major
// Tail quad (h4=360, M>=2): W loaded at clamped base HREAL-4 (uniform, no
// OOB, no inner-loop branch), acc slots remapped once after the loop.
// Lanes with tx*4 >= HACT are NON-OWNERS: they stay active (wave-uniform
// shuffles) but contribute 0 to the u reduction and skip stores.  <- r4 fix
// ---------------------------------------------------------------------------
template <int M, int HT>
__device__ __forceinline__ void prep_body(
    const float* __restrict__ s0, const float* __restrict__ s1, const float* __restrict__ s2,
    const float* __restrict__ W1_0, const float* __restrict__ b1_0, const float* __restrict__ W2_0,
    const float* __restrict__ W1_1, const float* __restrict__ b1_1, const float* __restrict__ W2_1,
    float* __restrict__ ws, float* __restrict__ xs) {
  constexpr int K     = (M == 2) ? 256 : 128;
  constexpr int HREAL = (M <= 1) ? H0c : H1c;
  constexpr int HP    = (M <= 1) ? H0c : HP1c;
  constexpr int WOFF  = (M == 1) ? 128 : (M == 3) ? 256 : 0;
  constexpr int HACT  = (M <= 1) ? 256 : 184;
  constexpr int EST   = (M <= 1) ? 0 : 1;

  const float* __restrict__ W    = (M <= 1) ? W1_0 : W1_1;
  const float* __restrict__ bias = (M == 1) ? b1_0 : (M == 3) ? b1_1 : nullptr;
  const float* __restrict__ W2   = (M <= 1) ? W2_0 : W2_1;

  const int i0  = blockIdx.x * 16;
  const int tx  = threadIdx.x;            // 0..63
  const int ty  = threadIdx.y;            // 0..3
  const int tid = ty * 64 + tx;

  // stage 16 input rows (M==2 concatenates s0|s1)
  {
    const float* __restrict__ sa = (M == 3) ? s2 : (M == 1) ? s1 : s0;
    constexpr int NF4 = 16 * (K / 4);
    for (int idx = tid; idx < NF4; idx += 256) {
      const int row = idx / (K / 4);
      const int c4  = (idx % (K / 4)) * 4;
      float4 v;
      if (M == 2 && c4 >= DIM)
        v = *(const float4*)&s1[(i0 + row) * DIM + (c4 - DIM)];
      else
        v = *(const float4*)&sa[(i0 + row) * DIM + c4];
      *(float4*)&xs[row * K + c4] = v;
    }
  }
  __syncthreads();

  const bool own   = (tx * 4 < HACT);            // tile ownership (r4 fix)
  const int  h4    = HT * HACT + tx * 4;
  const bool fullw = (h4 + 4 <= HREAL);
  const int  h4c   = fullw ? h4 : (HREAL - 4);   // uniform clamped load base
  const int  r0    = ty * 4;
  float acc[4][4] = {};
  const float* __restrict__ Wb = W + WOFF * HREAL + h4c;

  for (int d = 0; d < K; d += 4) {
    float4 xv[4];
    #pragma unroll
    for (int r = 0; r < 4; ++r) xv[r] = *(const float4*)&xs[(r0 + r) * K + d];
    float4 wv[4];
    #pragma unroll
    for (int dd = 0; dd < 4; ++dd)
      wv[dd] = *(const float4*)&Wb[(d + dd) * HREAL];
    #pragma unroll
    for (int dd = 0; dd < 4; ++dd) {
      #pragma unroll
      for (int r = 0; r < 4; ++r) {
        const float xval = ((const float*)&xv[r])[dd];
        acc[r][0] = fmaf(xval, wv[dd].x, acc[r][0]);
        acc[r][1] = fmaf(xval, wv[dd].y, acc[r][1]);
        acc[r][2] = fmaf(xval, wv[dd].z, acc[r][2]);
        acc[r][3] = fmaf(xval, wv[dd].w, acc[r][3]);
      }
    }
  }

  // tail remap: h4==HREAL-2 computed columns (HREAL-4..HREAL) shifted by 2
  if (M >= 2 && !fullw && h4 < HREAL) {
    #pragma unroll
    for (int r = 0; r < 4; ++r) {
      acc[r][0] = acc[r][2]; acc[r][1] = acc[r][3];
      acc[r][2] = 0.f;       acc[r][3] = 0.f;
    }
  }

  const bool ok0 = (h4 + 0 < HREAL), ok1 = (h4 + 1 < HREAL),
             ok2 = (h4 + 2 < HREAL), ok3 = (h4 + 3 < HREAL);

  float* __restrict__ outp = ws + ((M == 0) ? HX0_OFF : (M == 1) ? HYB0_OFF
                                 : (M == 2) ? HX1_OFF : HYB1_OFF);
  if (own && h4 < HP) {
    if ((M & 1) == 0) {   // panel layout
      const int pbase = (h4 >> 2) * (NROW * 4);
      #pragma unroll
      for (int r = 0; r < 4; ++r) {
        float4 v;
        v.x = ok0 ? acc[r][0] : 0.f;
        v.y = ok1 ? acc[r][1] : 0.f;
        v.z = ok2 ? acc[r][2] : 0.f;
        v.w = ok3 ? acc[r][3] : 0.f;
        *(float4*)&outp[pbase + (i0 + r0 + r) * 4] = v;
      }
    } else {              // row-major + bias (pad columns -> exact zero)
      float bv[4] = {0.f, 0.f, 0.f, 0.f};
      if (ok0) bv[0] = bias[h4 + 0];
      if (ok1) bv[1] = bias[h4 + 1];
      if (ok2) bv[2] = bias[h4 + 2];
      if (ok3) bv[3] = bias[h4 + 3];
      #pragma unroll
      for (int r = 0; r < 4; ++r) {
        float4 v;
        v.x = ok0 ? acc[r][0] + bv[0] : 0.f;
        v.y = ok1 ? acc[r][1] + bv[1] : 0.f;
        v.z = ok2 ? acc[r][2] + bv[2] : 0.f;
        v.w = ok3 ? acc[r][3] + bv[3] : 0.f;
        *(float4*)&outp[(i0 + r0 + r) * HP + h4] = v;
      }
    }
  }

  // u partial for hx tiles: u_part[i] = sum_{h in OWNED tile cols} W2[h]*hx[i,h]
  if ((M & 1) == 0) {
    float w2v[4];
    w2v[0] = (own && ok0) ? W2[h4 + 0] : 0.f;
    w2v[1] = (own && ok1) ? W2[h4 + 1] : 0.f;
    w2v[2] = (own && ok2) ? W2[h4 + 2] : 0.f;
    w2v[3] = (own && ok3) ? W2[h4 + 3] : 0.f;
    #pragma unroll
    for (int r = 0; r < 4; ++r) {
      float p = acc[r][0] * w2v[0] + acc[r][1] * w2v[1] +
                acc[r][2] * w2v[2] + acc[r][3] * w2v[3];
      #pragma unroll
      for (int off = 32; off > 0; off >>= 1) p += __shfl_xor(p, off);
      if (tx == 0)
        ws[UHP_OFF + EST * 1536 + HT * NROW + i0 + r0 + r] = p;
    }
  }
}

__global__ __launch_bounds__(256) void prep_kernel(
    const float* __restrict__ s0, const float* __restrict__ s1, const float* __restrict__ s2,
    const float* __restrict__ W1_0, const float* __restrict__ b1_0, const float* __restrict__ W2_0,
    const float* __restrict__ W1_1, const float* __restrict__ b1_1, const float* __restrict__ W2_1,
    float* __restrict__ ws) {
  __shared__ float xs[16 * 256];
  switch (blockIdx.y) {
    case 0: prep_body<0, 0>(s0, s1, s2, W1_0, b1_0, W2_0, W1_1, b1_1, W2_1, ws, xs); break;
    case 1: prep_body<1, 0>(s0, s1, s2, W1_0, b1_0, W2_0, W1_1, b1_1, W2_1, ws, xs); break;
    case 2: prep_body<2, 0>(s0, s1, s2, W1_0, b1_0, W2_0, W1_1, b1_1, W2_1, ws, xs); break;
    case 3: prep_body<2, 1>(s0, s1, s2, W1_0, b1_0, W2_0, W1_1, b1_1, W2_1, ws, xs); break;
    case 4: prep_body<3, 0>(s0, s1, s2, W1_0, b1_0, W2_0, W1_1, b1_1, W2_1, ws, xs); break;
    default: prep_body<3, 1>(s0, s1, s2, W1_0, b1_0, W2_0, W1_1, b1_1, W2_1, ws, xs); break;
  }
}

// ---------------------------------------------------------------------------
// pair: s[j,i] = 0.5*u_i + 0.5*sum_h w_h*|hx[i,h]+hyb[j,h]|; per-row partial
// max / sum-exp over an i-half.  2 VALU/elem; DS:VALU = 7:96 per quad (I=2).
// Block = 192 thr, each 2 i x 6 j.  Grid (128 jt, 2 iq, 2 est) = 512 blocks
// -> 2 blocks/CU (one est0 + one est1: balanced).
// ---------------------------------------------------------------------------
template <int HP, int HREAL, bool TWO>
__device__ __forceinline__ void pair_body(
    const float* __restrict__ hx4, const float* __restrict__ hyb,
    const float* __restrict__ W2, const float* __restrict__ uhp,
    float* __restrict__ pmax, float* __restrict__ psum, float* __restrict__ sdiag,
    float* sh) {
  float* ys   = sh;             // [6][HP]
  float* w2s  = sh + 6 * HP;    // [HP]
  float* redm = w2s + HP;       // [3][6]
  float* reds = redm + 18;      // [3][6]

  const int tid = threadIdx.x;          // 0..191
  const int j0  = blockIdx.x * 6;
  const int iq  = blockIdx.y;           // 0..1

  for (int idx = tid; idx < 6 * (HP / 4); idx += 192) {
    const int row = idx / (HP / 4);
    const int c4  = (idx % (HP / 4)) * 4;
    *(float4*)&ys[row * HP + c4] = *(const float4*)&hyb[(j0 + row) * HP + c4];
  }
  for (int q = tid; q < HP / 4; q += 192) {
    const int h = q * 4;
    float4 v;
    v.x = (h + 0 < HREAL) ? W2[h + 0] : 0.f;
    v.y = (h + 1 < HREAL) ? W2[h + 1] : 0.f;
    v.z = (h + 2 < HREAL) ? W2[h + 2] : 0.f;
    v.w = (h + 3 < HREAL) ? W2[h + 3] : 0.f;
    *(float4*)&w2s[h] = v;
  }
  __syncthreads();

  const int ia = iq * 384 + tid;
  const int ib = ia + 192;
  float ua = uhp[ia], ub = uhp[ib];
  if (TWO) { ua += uhp[NROW + ia]; ub += uhp[NROW + ib]; }
  ua *= 0.5f; ub *= 0.5f;

  float acca[6] = {0.f, 0.f, 0.f, 0.f, 0.f, 0.f};
  float accb[6] = {0.f, 0.f, 0.f, 0.f, 0.f, 0.f};
  const float* xa = hx4 + ia * 4;
  const float* xb = hx4 + ib * 4;
  #pragma unroll 2
  for (int hb = 0; hb < HP; hb += 4, xa += NROW * 4, xb += NROW * 4) {
    const float4 a = *(const float4*)xa;
    const float4 b = *(const float4*)xb;
    const float4 w = *(const float4*)&w2s[hb];
    #pragma unroll
    for (int r = 0; r < 6; ++r) {
      const float4 y = *(const float4*)&ys[r * HP + hb];
      acca[r] = fmaf(fabsf(a.x + y.x), w.x, acca[r]);
      acca[r] = fmaf(fabsf(a.y + y.y), w.y, acca[r]);
      acca[r] = fmaf(fabsf(a.z + y.z), w.z, acca[r]);
      acca[r] = fmaf(fabsf(a.w + y.w), w.w, acca[r]);
      accb[r] = fmaf(fabsf(b.x + y.x), w.x, accb[r]);
      accb[r] = fmaf(fabsf(b.y + y.y), w.y, accb[r]);
      accb[r] = fmaf(fabsf(b.z + y.z), w.z, accb[r]);
      accb[r] = fmaf(fabsf(b.w + y.w), w.w, accb[r]);
    }
  }

  float sa[6], sb[6];
  #pragma unroll
  for (int r = 0; r < 6; ++r) {
    sa[r] = fmaf(0.5f, acca[r], ua);
    sb[r] = fmaf(0.5f, accb[r], ub);
  }

  // diagonal s (t0 path; v_j and b2 cancel against lse)
  #pragma unroll
  for (int r = 0; r < 6; ++r) {
    if (ia == j0 + r) sdiag[ia] = sa[r];
    if (ib == j0 + r) sdiag[ib] = sb[r];
  }

  const int lane = tid & 63;
  const int wv   = tid >> 6;   // 0..2

  float M[6];
  #pragma unroll
  for (int r = 0; r < 6; ++r) {
    float mm = fmaxf(sa[r], sb[r]);
    #pragma unroll
    for (int off = 32; off > 0; off >>= 1) mm = fmaxf(mm, __shfl_xor(mm, off));
    M[r] = mm;
  }
  if (lane == 0) {
    #pragma unroll
    for (int r = 0; r < 6; ++r) redm[wv * 6 + r] = M[r];
  }
  __syncthreads();
  #pragma unroll
  for (int r = 0; r < 6; ++r)
    M[r] = fmaxf(fmaxf(redm[r], redm[6 + r]), redm[12 + r]);

  #pragma unroll
  for (int r = 0; r < 6; ++r) {
    float e = __expf(sa[r] - M[r]) + __expf(sb[r] - M[r]);
    #pragma unroll
    for (int off = 32; off > 0; off >>= 1) e += __shfl_xor(e, off);
    if (lane == 0) reds[wv * 6 + r] = e;
  }
  __syncthreads();
  if (tid < 6) {
    pmax[(j0 + tid) * 2 + iq] = fmaxf(fmaxf(redm[tid], redm[6 + tid]), redm[12 + tid]);
    psum[(j0 + tid) * 2 + iq] = reds[tid] + reds[6 + tid] + reds[12 + tid];
  }
}

__global__ __launch_bounds__(192) void pair_kernel(
    float* __restrict__ ws, const float* __restrict__ W2_0, const float* __restrict__ W2_1) {
  __shared__ float sh[6 * HP1c + HP1c + 36];
  if (blockIdx.z == 0)
    pair_body<H0c, H0c, false>(ws + HX0_OFF, ws + HYB0_OFF, W2_0, ws + UHP_OFF,
                               ws + PMAX_OFF, ws + PSUM_OFF, ws + DIAG_OFF, sh);
  else
    pair_body<HP1c, H1c, true>(ws + HX1_OFF, ws + HYB1_OFF, W2_1, ws + UHP_OFF + 1536,
                               ws + PMAX_OFF + 1536, ws + PSUM_OFF + 1536,
                               ws + DIAG_OFF + NROW, sh);
}

// ---------------------------------------------------------------------------
// final: merge 2 i-half partials -> lse per row; sum (s_diag - lse); scalar.
// ---------------------------------------------------------------------------
__global__ __launch_bounds__(1024) void final_kernel(
    const float* __restrict__ ws, float* __restrict__ out) {
  __shared__ float red[1024];
  const int t = threadIdx.x;
  float val = 0.f;
  if (t < NROW) {
    #pragma unroll
    for (int est = 0; est < 2; ++est) {
      const float* pm = ws + PMAX_OFF + est * 1536 + t * 2;
      const float* ps = ws + PSUM_OFF + est * 1536 + t * 2;
      float M = fmaxf(pm[0], pm[1]);
      float S = ps[0] * __expf(pm[0] - M) + ps[1] * __expf(pm[1] - M);
      float lse = M + logf(S);
      val += ws[DIAG_OFF + est * NROW + t] - lse;
    }
  }
  red[t] = val;
  __syncthreads();
  for (int sdown = 512; sdown > 0; sdown >>= 1) {
    if (t < sdown) red[t] += red[t + sdown];
    __syncthreads();
  }
  if (t == 0) out[0] = red[0] * (1.0f / (float)NROW) + 2.0f * logf((float)NROW);
}

// ---------------------------------------------------------------------------
extern "C" void kernel_launch(void* const* d_in, const int* in_sizes, int n_in,
                              void* d_out, int out_size, void* d_ws, size_t ws_size,
                              hipStream_t stream) {
  const float* s0   = (const float*)d_in[0];
  const float* s1   = (const float*)d_in[1];
  const float* s2   = (const float*)d_in[2];
  const float* W1_0 = (const float*)d_in[3];
  const float* b1_0 = (const float*)d_in[4];
  const float* W2_0 = (const float*)d_in[5];
  const float* W1_1 = (const float*)d_in[7];
  const float* b1_1 = (const float*)d_in[8];
  const float* W2_1 = (const float*)d_in[9];
  float* ws  = (float*)d_ws;
  float* out = (float*)d_out;

  hipLaunchKernelGGL(prep_kernel, dim3(48, 6), dim3(64, 4), 0, stream,
                     s0, s1, s2, W1_0, b1_0, W2_0, W1_1, b1_1, W2_1, ws);
  hipLaunchKernelGGL(pair_kernel, dim3(128, 2, 2), dim3(192), 0, stream,
                     ws, W2_0, W2_1);
  hipLaunchKernelGGL(final_kernel, dim3(1), dim3(1024), 0, stream, ws, out);
}

// Round 6
// 68.173 us; speedup vs baseline: 1.2320x; 1.2206x over previous
//
#include <hip/hip_runtime.h>
#include <math.h>

#define NROW 768
#define DIM  128

constexpr int H0c  = 256;
constexpr int H1c  = 362;
constexpr int HP1c = 368;   // H1 padded; pad columns are exact zeros

// Workspace layout (float offsets). ~3.9 MB total.
// hx stored in PANEL layout: [HP/4][768][4] so the pair kernel's per-thread
// read hx[i, hb..hb+3] is one coalesced float4 (lane = i).
constexpr int HX0_OFF  = 0;         // [64][768][4]
constexpr int HYB0_OFF = 196608;    // [768][256]   hy0 + b1_0 (row-major)
constexpr int HX1_OFF  = 393216;    // [92][768][4]
constexpr int HYB1_OFF = 675840;    // [768][368]   hy1 + b1_1 (row-major)
constexpr int PMAX_OFF = 958464;    // [2][768][2]  per-iq-half row max
constexpr int PSUM_OFF = 961536;    // [2][768][2]
constexpr int DIAG_OFF = 964608;    // [2][768]     s_diag
constexpr int UHP_OFF  = 966144;    // [2][2][768]  u partials (est, ht)

// ---------------------------------------------------------------------------
// prep: four projections (256 thr, 4h x 4rows, 16 fma chains / thread).
//   M=0: hx0  = s0 @ W1_0[0:128]            -> panel  (+ u0 partial)
//   M=1: hyb0 = s1 @ W1_0[128:256] + b1_0   -> row-major
//   M=2: hx1  = [s0|s1] @ W1_1[0:256]       -> panel  (+ u1 partials)
//   M=3: hyb1 = s2 @ W1_1[256:384] + b1_1   -> row-major
// Tail quad (h4=360, M>=2): W loaded at clamped base HREAL-4 (uniform, no
// OOB, no inner-loop branch), acc slots remapped once after the loop.
// Lanes with tx*4 >= HACT are NON-OWNERS: active for shuffles, zero
// contribution to u, no stores.
// ---------------------------------------------------------------------------
template <int M, int HT>
__device__ __forceinline__ void prep_body(
    const float* __restrict__ s0, const float* __restrict__ s1, const float* __restrict__ s2,
    const float* __restrict__ W1_0, const float* __restrict__ b1_0, const float* __restrict__ W2_0,
    const float* __restrict__ W1_1, const float* __restrict__ b1_1, const float* __restrict__ W2_1,
    float* __restrict__ ws, float* __restrict__ xs) {
  constexpr int K     = (M == 2) ? 256 : 128;
  constexpr int HREAL = (M <= 1) ? H0c : H1c;
  constexpr int HP    = (M <= 1) ? H0c : HP1c;
  constexpr int WOFF  = (M == 1) ? 128 : (M == 3) ? 256 : 0;
  constexpr int HACT  = (M <= 1) ? 256 : 184;
  constexpr int EST   = (M <= 1) ? 0 : 1;

  const float* __restrict__ W    = (M <= 1) ? W1_0 : W1_1;
  const float* __restrict__ bias = (M == 1) ? b1_0 : (M == 3) ? b1_1 : nullptr;
  const float* __restrict__ W2   = (M <= 1) ? W2_0 : W2_1;

  const int i0  = blockIdx.x * 16;
  const int tx  = threadIdx.x;            // 0..63
  const int ty  = threadIdx.y;            // 0..3
  const int tid = ty * 64 + tx;

  // stage 16 input rows (M==2 concatenates s0|s1)
  {
    const float* __restrict__ sa = (M == 3) ? s2 : (M == 1) ? s1 : s0;
    constexpr int NF4 = 16 * (K / 4);
    for (int idx = tid; idx < NF4; idx += 256) {
      const int row = idx / (K / 4);
      const int c4  = (idx % (K / 4)) * 4;
      float4 v;
      if (M == 2 && c4 >= DIM)
        v = *(const float4*)&s1[(i0 + row) * DIM + (c4 - DIM)];
      else
        v = *(const float4*)&sa[(i0 + row) * DIM + c4];
      *(float4*)&xs[row * K + c4] = v;
    }
  }
  __syncthreads();

  const bool own   = (tx * 4 < HACT);            // tile ownership
  const int  h4    = HT * HACT + tx * 4;
  const bool fullw = (h4 + 4 <= HREAL);
  const int  h4c   = fullw ? h4 : (HREAL - 4);   // uniform clamped load base
  const int  r0    = ty * 4;
  float acc[4][4] = {};
  const float* __restrict__ Wb = W + WOFF * HREAL + h4c;

  for (int d = 0; d < K; d += 4) {
    float4 xv[4];
    #pragma unroll
    for (int r = 0; r < 4; ++r) xv[r] = *(const float4*)&xs[(r0 + r) * K + d];
    float4 wv[4];
    #pragma unroll
    for (int dd = 0; dd < 4; ++dd)
      wv[dd] = *(const float4*)&Wb[(d + dd) * HREAL];
    #pragma unroll
    for (int dd = 0; dd < 4; ++dd) {
      #pragma unroll
      for (int r = 0; r < 4; ++r) {
        const float xval = ((const float*)&xv[r])[dd];
        acc[r][0] = fmaf(xval, wv[dd].x, acc[r][0]);
        acc[r][1] = fmaf(xval, wv[dd].y, acc[r][1]);
        acc[r][2] = fmaf(xval, wv[dd].z, acc[r][2]);
        acc[r][3] = fmaf(xval, wv[dd].w, acc[r][3]);
      }
    }
  }

  // tail remap: h4==HREAL-2 computed columns (HREAL-4..HREAL) shifted by 2
  if (M >= 2 && !fullw && h4 < HREAL) {
    #pragma unroll
    for (int r = 0; r < 4; ++r) {
      acc[r][0] = acc[r][2]; acc[r][1] = acc[r][3];
      acc[r][2] = 0.f;       acc[r][3] = 0.f;
    }
  }

  const bool ok0 = (h4 + 0 < HREAL), ok1 = (h4 + 1 < HREAL),
             ok2 = (h4 + 2 < HREAL), ok3 = (h4 + 3 < HREAL);

  float* __restrict__ outp = ws + ((M == 0) ? HX0_OFF : (M == 1) ? HYB0_OFF
                                 : (M == 2) ? HX1_OFF : HYB1_OFF);
  if (own && h4 < HP) {
    if ((M & 1) == 0) {   // panel layout
      const int pbase = (h4 >> 2) * (NROW * 4);
      #pragma unroll
      for (int r = 0; r < 4; ++r) {
        float4 v;
        v.x = ok0 ? acc[r][0] : 0.f;
        v.y = ok1 ? acc[r][1] : 0.f;
        v.z = ok2 ? acc[r][2] : 0.f;
        v.w = ok3 ? acc[r][3] : 0.f;
        *(float4*)&outp[pbase + (i0 + r0 + r) * 4] = v;
      }
    } else {              // row-major + bias (pad columns -> exact zero)
      float bv[4] = {0.f, 0.f, 0.f, 0.f};
      if (ok0) bv[0] = bias[h4 + 0];
      if (ok1) bv[1] = bias[h4 + 1];
      if (ok2) bv[2] = bias[h4 + 2];
      if (ok3) bv[3] = bias[h4 + 3];
      #pragma unroll
      for (int r = 0; r < 4; ++r) {
        float4 v;
        v.x = ok0 ? acc[r][0] + bv[0] : 0.f;
        v.y = ok1 ? acc[r][1] + bv[1] : 0.f;
        v.z = ok2 ? acc[r][2] + bv[2] : 0.f;
        v.w = ok3 ? acc[r][3] + bv[3] : 0.f;
        *(float4*)&outp[(i0 + r0 + r) * HP + h4] = v;
      }
    }
  }

  // u partial for hx tiles: u_part[i] = sum_{h in OWNED tile cols} W2[h]*hx[i,h]
  if ((M & 1) == 0) {
    float w2v[4];
    w2v[0] = (own && ok0) ? W2[h4 + 0] : 0.f;
    w2v[1] = (own && ok1) ? W2[h4 + 1] : 0.f;
    w2v[2] = (own && ok2) ? W2[h4 + 2] : 0.f;
    w2v[3] = (own && ok3) ? W2[h4 + 3] : 0.f;
    #pragma unroll
    for (int r = 0; r < 4; ++r) {
      float p = acc[r][0] * w2v[0] + acc[r][1] * w2v[1] +
                acc[r][2] * w2v[2] + acc[r][3] * w2v[3];
      #pragma unroll
      for (int off = 32; off > 0; off >>= 1) p += __shfl_xor(p, off);
      if (tx == 0)
        ws[UHP_OFF + EST * 1536 + HT * NROW + i0 + r0 + r] = p;
    }
  }
}

__global__ __launch_bounds__(256) void prep_kernel(
    const float* __restrict__ s0, const float* __restrict__ s1, const float* __restrict__ s2,
    const float* __restrict__ W1_0, const float* __restrict__ b1_0, const float* __restrict__ W2_0,
    const float* __restrict__ W1_1, const float* __restrict__ b1_1, const float* __restrict__ W2_1,
    float* __restrict__ ws) {
  __shared__ float xs[16 * 256];
  switch (blockIdx.y) {
    case 0: prep_body<0, 0>(s0, s1, s2, W1_0, b1_0, W2_0, W1_1, b1_1, W2_1, ws, xs); break;
    case 1: prep_body<1, 0>(s0, s1, s2, W1_0, b1_0, W2_0, W1_1, b1_1, W2_1, ws, xs); break;
    case 2: prep_body<2, 0>(s0, s1, s2, W1_0, b1_0, W2_0, W1_1, b1_1, W2_1, ws, xs); break;
    case 3: prep_body<2, 1>(s0, s1, s2, W1_0, b1_0, W2_0, W1_1, b1_1, W2_1, ws, xs); break;
    case 4: prep_body<3, 0>(s0, s1, s2, W1_0, b1_0, W2_0, W1_1, b1_1, W2_1, ws, xs); break;
    default: prep_body<3, 1>(s0, s1, s2, W1_0, b1_0, W2_0, W1_1, b1_1, W2_1, ws, xs); break;
  }
}

// ---------------------------------------------------------------------------
// pair: s[j,i] = 0.5*u_i + 0.5*sum_h w_h*|hx[i,h]+hyb[j,h]|; per-row partial
// max / sum-exp over an i-half.  2 VALU/elem (v_add + v_fma with |.| mod).
// Block = 192 thr (launch_bounds min-waves=2 -> VGPR headroom for
// pipelining), each thread 2 i x 6 j.  Global hx prefetched one quad ahead
// (an/bn double-buffer, last quad peeled); unroll 4 interleaves LDS
// broadcasts + FMAs across quads.  Grid (128 jt, 2 iq, 2 est) = 512 blocks
// -> 2 blocks/CU (one est0 + one est1 per CU: balanced).
// ---------------------------------------------------------------------------
template <int HP, int HREAL, bool TWO>
__device__ __forceinline__ void pair_body(
    const float* __restrict__ hx4, const float* __restrict__ hyb,
    const float* __restrict__ W2, const float* __restrict__ uhp,
    float* __restrict__ pmax, float* __restrict__ psum, float* __restrict__ sdiag,
    float* sh) {
  float* ys   = sh;             // [6][HP]
  float* w2s  = sh + 6 * HP;    // [HP]
  float* redm = w2s + HP;       // [3][6]
  float* reds = redm + 18;      // [3][6]

  const int tid = threadIdx.x;          // 0..191
  const int j0  = blockIdx.x * 6;
  const int iq  = blockIdx.y;           // 0..1

  for (int idx = tid; idx < 6 * (HP / 4); idx += 192) {
    const int row = idx / (HP / 4);
    const int c4  = (idx % (HP / 4)) * 4;
    *(float4*)&ys[row * HP + c4] = *(const float4*)&hyb[(j0 + row) * HP + c4];
  }
  for (int q = tid; q < HP / 4; q += 192) {
    const int h = q * 4;
    float4 v;
    v.x = (h + 0 < HREAL) ? W2[h + 0] : 0.f;
    v.y = (h + 1 < HREAL) ? W2[h + 1] : 0.f;
    v.z = (h + 2 < HREAL) ? W2[h + 2] : 0.f;
    v.w = (h + 3 < HREAL) ? W2[h + 3] : 0.f;
    *(float4*)&w2s[h] = v;
  }
  __syncthreads();

  const int ia = iq * 384 + tid;
  const int ib = ia + 192;
  float ua = uhp[ia], ub = uhp[ib];
  if (TWO) { ua += uhp[NROW + ia]; ub += uhp[NROW + ib]; }
  ua *= 0.5f; ub *= 0.5f;

  float acca[6] = {0.f, 0.f, 0.f, 0.f, 0.f, 0.f};
  float accb[6] = {0.f, 0.f, 0.f, 0.f, 0.f, 0.f};

  auto do_quad = [&](int hb, const float4& a, const float4& b) {
    const float4 w = *(const float4*)&w2s[hb];
    #pragma unroll
    for (int r = 0; r < 6; ++r) {
      const float4 y = *(const float4*)&ys[r * HP + hb];
      acca[r] = fmaf(fabsf(a.x + y.x), w.x, acca[r]);
      acca[r] = fmaf(fabsf(a.y + y.y), w.y, acca[r]);
      acca[r] = fmaf(fabsf(a.z + y.z), w.z, acca[r]);
      acca[r] = fmaf(fabsf(a.w + y.w), w.w, acca[r]);
      accb[r] = fmaf(fabsf(b.x + y.x), w.x, accb[r]);
      accb[r] = fmaf(fabsf(b.y + y.y), w.y, accb[r]);
      accb[r] = fmaf(fabsf(b.z + y.z), w.z, accb[r]);
      accb[r] = fmaf(fabsf(b.w + y.w), w.w, accb[r]);
    }
  };

  const float* xa = hx4 + ia * 4;
  const float* xb = hx4 + ib * 4;
  float4 an = *(const float4*)xa;       // prefetch quad 0
  float4 bn = *(const float4*)xb;
  #pragma unroll 4
  for (int hb = 0; hb < HP - 4; hb += 4) {
    const float4 a = an;
    const float4 b = bn;
    xa += NROW * 4; xb += NROW * 4;
    an = *(const float4*)xa;            // prefetch next quad
    bn = *(const float4*)xb;
    do_quad(hb, a, b);
  }
  do_quad(HP - 4, an, bn);              // peeled last quad

  float sa[6], sb[6];
  #pragma unroll
  for (int r = 0; r < 6; ++r) {
    sa[r] = fmaf(0.5f, acca[r], ua);
    sb[r] = fmaf(0.5f, accb[r], ub);
  }

  // diagonal s (t0 path; v_j and b2 cancel against lse)
  #pragma unroll
  for (int r = 0; r < 6; ++r) {
    if (ia == j0 + r) sdiag[ia] = sa[r];
    if (ib == j0 + r) sdiag[ib] = sb[r];
  }

  const int lane = tid & 63;
  const int wv   = tid >> 6;   // 0..2

  float M[6];
  #pragma unroll
  for (int r = 0; r < 6; ++r) {
    float mm = fmaxf(sa[r], sb[r]);
    #pragma unroll
    for (int off = 32; off > 0; off >>= 1) mm = fmaxf(mm, __shfl_xor(mm, off));
    M[r] = mm;
  }
  if (lane == 0) {
    #pragma unroll
    for (int r = 0; r < 6; ++r) redm[wv * 6 + r] = M[r];
  }
  __syncthreads();
  #pragma unroll
  for (int r = 0; r < 6; ++r)
    M[r] = fmaxf(fmaxf(redm[r], redm[6 + r]), redm[12 + r]);

  #pragma unroll
  for (int r = 0; r < 6; ++r) {
    float e = __expf(sa[r] - M[r]) + __expf(sb[r] - M[r]);
    #pragma unroll
    for (int off = 32; off > 0; off >>= 1) e += __shfl_xor(e, off);
    if (lane == 0) reds[wv * 6 + r] = e;
  }
  __syncthreads();
  if (tid < 6) {
    pmax[(j0 + tid) * 2 + iq] = fmaxf(fmaxf(redm[tid], redm[6 + tid]), redm[12 + tid]);
    psum[(j0 + tid) * 2 + iq] = reds[tid] + reds[6 + tid] + reds[12 + tid];
  }
}

__global__ __launch_bounds__(192, 2) void pair_kernel(
    float* __restrict__ ws, const float* __restrict__ W2_0, const float* __restrict__ W2_1) {
  __shared__ float sh[6 * HP1c + HP1c + 36];
  if (blockIdx.z == 0)
    pair_body<H0c, H0c, false>(ws + HX0_OFF, ws + HYB0_OFF, W2_0, ws + UHP_OFF,
                               ws + PMAX_OFF, ws + PSUM_OFF, ws + DIAG_OFF, sh);
  else
    pair_body<HP1c, H1c, true>(ws + HX1_OFF, ws + HYB1_OFF, W2_1, ws + UHP_OFF + 1536,
                               ws + PMAX_OFF + 1536, ws + PSUM_OFF + 1536,
                               ws + DIAG_OFF + NROW, sh);
}

// ---------------------------------------------------------------------------
// final: merge 2 i-half partials -> lse per row; sum (s_diag - lse); scalar.
// ---------------------------------------------------------------------------
__global__ __launch_bounds__(1024) void final_kernel(
    const float* __restrict__ ws, float* __restrict__ out) {
  __shared__ float red[1024];
  const int t = threadIdx.x;
  float val = 0.f;
  if (t < NROW) {
    #pragma unroll
    for (int est = 0; est < 2; ++est) {
      const float* pm = ws + PMAX_OFF + est * 1536 + t * 2;
      const float* ps = ws + PSUM_OFF + est * 1536 + t * 2;
      float M = fmaxf(pm[0], pm[1]);
      float S = ps[0] * __expf(pm[0] - M) + ps[1] * __expf(pm[1] - M);
      float lse = M + logf(S);
      val += ws[DIAG_OFF + est * NROW + t] - lse;
    }
  }
  red[t] = val;
  __syncthreads();
  for (int sdown = 512; sdown > 0; sdown >>= 1) {
    if (t < sdown) red[t] += red[t + sdown];
    __syncthreads();
  }
  if (t == 0) out[0] = red[0] * (1.0f / (float)NROW) + 2.0f * logf((float)NROW);
}

// ---------------------------------------------------------------------------
extern "C" void kernel_launch(void* const* d_in, const int* in_sizes, int n_in,
                              void* d_out, int out_size, void* d_ws, size_t ws_size,
                              hipStream_t stream) {
  const float* s0   = (const float*)d_in[0];
  const float* s1   = (const float*)d_in[1];
  const float* s2   = (const float*)d_in[2];
  const float* W1_0 = (const float*)d_in[3];
  const float* b1_0 = (const float*)d_in[4];
  const float* W2_0 = (const float*)d_in[5];
  const float* W1_1 = (const float*)d_in[7];
  const float* b1_1 = (const float*)d_in[8];
  const float* W2_1 = (const float*)d_in[9];
  float* ws  = (float*)d_ws;
  float* out = (float*)d_out;

  hipLaunchKernelGGL(prep_kernel, dim3(48, 6), dim3(64, 4), 0, stream,
                     s0, s1, s2, W1_0, b1_0, W2_0, W1_1, b1_1, W2_1, ws);
  hipLaunchKernelGGL(pair_kernel, dim3(128, 2, 2), dim3(192), 0, stream,
                     ws, W2_0, W2_1);
  hipLaunchKernelGGL(final_kernel, dim3(1), dim3(1024), 0, stream, ws, out);
}